// Round 17
// baseline (547.163 us; speedup 1.0000x reference)
//
#include <hip/hip_runtime.h>
#include <hip/hip_bf16.h>
#include <stdint.h>

#define B_ 4
#define S_ 1024
#define D_ 1024
#define H_ 4096
#define E_ 8
#define T_ (B_*S_)   // 4096 tokens

#define BK 64        // 128 bytes bf16 per row per K-tile
#define MAXT1 1152   // 72 mtiles(128) x 16 nt(256)
#define MAXT2 1152   // 72 mtiles(128) x 8 nt(128) x 2 splits
#define T1BLK 8192
#define T2BLK 8192

typedef __bf16 bf16x8 __attribute__((ext_vector_type(8)));
typedef float f32x4 __attribute__((ext_vector_type(4)));
typedef unsigned short ushort8 __attribute__((ext_vector_type(8)));
typedef unsigned short ushort4v __attribute__((ext_vector_type(4)));

__device__ __forceinline__ unsigned short f2bf(float f) {
  union { float f; uint32_t u; } v; v.f = f;
  uint32_t u = v.u;
  u += 0x7fff + ((u >> 16) & 1);   // round-to-nearest-even
  return (unsigned short)(u >> 16);
}

__device__ __forceinline__ void gl16(const void* g, void* l) {
  __builtin_amdgcn_global_load_lds(
      (const __attribute__((address_space(1))) void*)g,
      (__attribute__((address_space(3))) void*)l,
      16, 0, 0);
}

// ---- shared transpose tile body: fp32 [R][C] slab e -> bf16 [C][R] ----
__device__ __forceinline__ void transpose_tile(
    const float* __restrict__ in, unsigned short* __restrict__ outp,
    int R, int C, int e, int r0, int c0, int t,
    unsigned short (*tile)[66]) {
  const size_t eoff = (size_t)e * R * C;
  {
    const int r = t >> 2, cseg = (t & 3) * 16;
    const float4* s4 = (const float4*)(in + eoff + (size_t)(r0 + r) * C + (c0 + cseg));
    float4 v0 = s4[0], v1 = s4[1], v2 = s4[2], v3 = s4[3];
    ushort8 w0, w1;
    w0[0]=f2bf(v0.x); w0[1]=f2bf(v0.y); w0[2]=f2bf(v0.z); w0[3]=f2bf(v0.w);
    w0[4]=f2bf(v1.x); w0[5]=f2bf(v1.y); w0[6]=f2bf(v1.z); w0[7]=f2bf(v1.w);
    w1[0]=f2bf(v2.x); w1[1]=f2bf(v2.y); w1[2]=f2bf(v2.z); w1[3]=f2bf(v2.w);
    w1[4]=f2bf(v3.x); w1[5]=f2bf(v3.y); w1[6]=f2bf(v3.z); w1[7]=f2bf(v3.w);
    *(ushort8*)&tile[r][cseg]     = w0;
    *(ushort8*)&tile[r][cseg + 8] = w1;
  }
  __syncthreads();
  {
    const int c = t >> 2, rseg = (t & 3) * 16;
    ushort8 w0, w1;
#pragma unroll
    for (int j = 0; j < 8; ++j) {
      w0[j] = tile[rseg + j][c];
      w1[j] = tile[rseg + 8 + j][c];
    }
    unsigned short* dst = outp + eoff + (size_t)(c0 + c) * R + (r0 + rseg);
    *(ushort8*)dst       = w0;
    *(ushort8*)(dst + 8) = w1;
  }
}

__global__ __launch_bounds__(256) void transpose_conv(
    const float* __restrict__ in, unsigned short* __restrict__ outp,
    int R, int C) {
  __shared__ unsigned short tile[64][66];
  transpose_tile(in, outp, R, C, blockIdx.z, blockIdx.y * 64, blockIdx.x * 64,
                 threadIdx.x, tile);
}

// ---------------- gating + x->bf16 fused, with W1-transpose blocks appended --
__global__ __launch_bounds__(256) void gate_t1_kernel(
    const float* __restrict__ x, const float* __restrict__ Wg,
    const float* __restrict__ bg, float* __restrict__ scores,
    unsigned short* __restrict__ xb,
    int* __restrict__ cnt, int* __restrict__ lists,
    const float* __restrict__ W1, unsigned short* __restrict__ WT1) {
  __shared__ unsigned short tile[64][66];
  if (blockIdx.x >= T_ / 4) {
    int bid = blockIdx.x - T_ / 4;
    int e = bid >> 10, rem = bid & 1023;
    int cx = rem & 63, ry = rem >> 6;
    transpose_tile(W1, WT1, D_, H_, e, ry * 64, cx * 64, threadIdx.x, tile);
    return;
  }
  int t = blockIdx.x * 4 + (threadIdx.x >> 6);
  int l = threadIdx.x & 63;
  float acc[E_];
#pragma unroll
  for (int e = 0; e < E_; ++e) acc[e] = 0.f;
  const float* xr = x + (size_t)t * D_;
  unsigned short* xbr = xb + (size_t)t * D_;
  for (int k4 = l * 4; k4 < D_; k4 += 256) {
    float4 xv = *(const float4*)(xr + k4);
    ushort4v wq;
    wq[0] = f2bf(xv.x); wq[1] = f2bf(xv.y); wq[2] = f2bf(xv.z); wq[3] = f2bf(xv.w);
    *(ushort4v*)(xbr + k4) = wq;
#pragma unroll
    for (int q = 0; q < 4; ++q) {
      float xs = (q == 0) ? xv.x : (q == 1) ? xv.y : (q == 2) ? xv.z : xv.w;
      const float4* w = (const float4*)(Wg + (size_t)(k4 + q) * E_);
      float4 w0 = w[0], w1 = w[1];
      acc[0] += xs * w0.x; acc[1] += xs * w0.y; acc[2] += xs * w0.z; acc[3] += xs * w0.w;
      acc[4] += xs * w1.x; acc[5] += xs * w1.y; acc[6] += xs * w1.z; acc[7] += xs * w1.w;
    }
  }
#pragma unroll
  for (int off = 32; off > 0; off >>= 1)
#pragma unroll
    for (int e = 0; e < E_; ++e) acc[e] += __shfl_xor(acc[e], off, 64);
  if (l == 0) {
    float s[E_];
#pragma unroll
    for (int e = 0; e < E_; ++e) {
      s[e] = acc[e] + bg[e];
      scores[(size_t)t * E_ + e] = s[e];
    }
    int i1 = 0; float m1 = -1e30f;
#pragma unroll
    for (int e = 0; e < E_; ++e) if (s[e] > m1) { m1 = s[e]; i1 = e; }
    int i2 = -1; float m2 = -1e30f;
#pragma unroll
    for (int e = 0; e < E_; ++e) if (e != i1 && s[e] > m2) { m2 = s[e]; i2 = e; }
    int p1 = atomicAdd(&cnt[i1], 1); lists[i1 * T_ + p1] = t;
    int p2 = atomicAdd(&cnt[i2], 1); lists[i2 * T_ + p2] = t;
  }
}

// scan, parallel. mtiles at 128-row granularity.
// G1 word: e<<16 | mt<<8 | nt          (nt < 16, BN=256)
// G2 word: e<<16 | mt<<8 | sp<<6 | nt  (nt < 8, BN=128, sp < 2)
__global__ void scan_kernel(const int* __restrict__ cnt, int* __restrict__ off,
                            int* __restrict__ hdr, int* __restrict__ t1tab,
                            int* __restrict__ t2tab) {
  int mt[E_], offl[E_];
  int o = 0;
  for (int e = 0; e < E_; ++e) {
    offl[e] = o; o += cnt[e];
    mt[e] = (cnt[e] + 127) / 128;
  }
  const int t = threadIdx.x;
  if (t < 128) {
    int e = t >> 4, nt = t & 15;
    int s1 = 0;
    for (int q = 0; q < e; ++q) s1 += mt[q] * 16;
    int base = s1 + nt * mt[e];
    for (int m = 0; m < mt[e]; ++m) t1tab[base + m] = (e << 16) | (m << 8) | nt;
  } else {
    int t2 = t - 128;
    int e = t2 >> 4, idx = t2 & 15, sp = idx >> 3, nt = idx & 7;
    int s2 = 0;
    for (int q = 0; q < e; ++q) s2 += mt[q] * 16;
    int base = s2 + (sp * 8 + nt) * mt[e];
    for (int m = 0; m < mt[e]; ++m)
      t2tab[base + m] = (e << 16) | (m << 8) | (sp << 6) | nt;
  }
  if (t == 0) {
    int s1 = 0;
    for (int e = 0; e < E_; ++e) { s1 += mt[e] * 16; off[e] = offl[e]; }
    hdr[0] = s1; hdr[1] = s1;
  }
}

// ---------------- GEMM1: 128(M) x 256(N) tile, single-buffer, 48KB LDS -------
// (R14-confirmed fastest G1 config; explicit 3 blocks/CU)
template <bool FUSET2>
__global__ __launch_bounds__(256, 3) void ffn_gemm1(
    const unsigned short* __restrict__ xb,
    const unsigned short* __restrict__ WT,
    const float* __restrict__ bias,
    const int* __restrict__ cnt, const int* __restrict__ off,
    const int* __restrict__ lists,
    const int* __restrict__ tab, const int* __restrict__ hdr,
    unsigned short* __restrict__ hout,
    const float* __restrict__ Wsrc, unsigned short* __restrict__ WTdst)
{
  constexpr int K = D_;      // 1024
  constexpr int N = H_;      // 4096
  constexpr int NT = K / BK; // 16

  __shared__ unsigned short sA[128 * BK];   // 16 KB
  __shared__ unsigned short sB[256 * BK];   // 32 KB

  if (FUSET2 && blockIdx.x >= MAXT1) {
    int bid = blockIdx.x - MAXT1;
    int e = bid >> 10, rem = bid & 1023;
    int cx = rem & 15, ry = rem >> 4;
    transpose_tile(Wsrc, WTdst, H_, D_, e, ry * 64, cx * 64, threadIdx.x,
                   (unsigned short (*)[66])sB);
    return;
  }

  const int ntask = hdr[0];
  const int b = blockIdx.x;
  if (b >= ntask) return;
  const int q = ntask >> 3, r = ntask & 7;
  const int x = b & 7, ii = b >> 3;
  const int task = (x < r ? x * (q + 1) : r * (q + 1) + (x - r) * q) + ii;

  const int ent = tab[task];
  const int e  = ent >> 16;
  const int m0 = ((ent >> 8) & 0xff) * 128;
  const int n0 = (ent & 63) * 256;
  const int count = cnt[e];
  const int oe = off[e];
  const int* lst = lists + e * T_;

  const int tid  = threadIdx.x;
  const int lane = tid & 63;
  const int wv   = tid >> 6;
  const int wm   = (wv >> 1) * 64;     // 0 / 64
  const int wn   = (wv & 1) * 128;     // 0 / 128

  const int srow   = lane >> 3;
  const int schunk = (lane & 7) * 16;
  const int sgoff  = schunk ^ (srow << 4);

  const char* arow[4];
  const char* brow[8];
#pragma unroll
  for (int i = 0; i < 4; ++i) {
    int rr = i * 32 + wv * 8 + srow;
    int gr = m0 + rr;
    int tok = (gr < count) ? lst[gr] : lst[m0];
    arow[i] = (const char*)(xb + (size_t)tok * K);
  }
#pragma unroll
  for (int i = 0; i < 8; ++i) {
    int rr = i * 32 + wv * 8 + srow;
    brow[i] = (const char*)(WT + (size_t)e * N * K + (size_t)(n0 + rr) * K);
  }

  const int lrow = lane & 15;
  const int kg   = lane >> 4;
  const int fswz = (lrow & 7) << 4;

  f32x4 acc[4][8];
#pragma unroll
  for (int i = 0; i < 4; ++i)
#pragma unroll
    for (int j = 0; j < 8; ++j) acc[i][j] = (f32x4){0.f, 0.f, 0.f, 0.f};

#pragma unroll 1
  for (int t = 0; t < NT; ++t) {
    const int kb = t * 128;   // bytes along K
#pragma unroll
    for (int i = 0; i < 4; ++i)
      gl16(arow[i] + kb + sgoff, (char*)sA + (i * 32 + wv * 8) * 128);
#pragma unroll
    for (int i = 0; i < 8; ++i)
      gl16(brow[i] + kb + sgoff, (char*)sB + (i * 32 + wv * 8) * 128);
    __syncthreads();
#pragma unroll
    for (int ks = 0; ks < 2; ++ks) {
      bf16x8 af[4], bfm[8];
      const int kbyte = ks * 64 + kg * 16;
#pragma unroll
      for (int i = 0; i < 4; ++i)
        af[i] = *(const bf16x8*)((const char*)sA + (wm + i * 16 + lrow) * 128 + (kbyte ^ fswz));
#pragma unroll
      for (int j = 0; j < 8; ++j)
        bfm[j] = *(const bf16x8*)((const char*)sB + (wn + j * 16 + lrow) * 128 + (kbyte ^ fswz));
#pragma unroll
      for (int i = 0; i < 4; ++i)
#pragma unroll
        for (int j = 0; j < 8; ++j)
          acc[i][j] = __builtin_amdgcn_mfma_f32_16x16x32_bf16(af[i], bfm[j], acc[i][j], 0, 0, 0);
    }
    __syncthreads();
  }

  const int rbase = 4 * kg;
#pragma unroll
  for (int i = 0; i < 4; ++i) {
#pragma unroll
    for (int r2 = 0; r2 < 4; ++r2) {
      int row  = wm + i * 16 + rbase + r2;
      int grow = m0 + row;
      if (grow < count) {
#pragma unroll
        for (int j = 0; j < 8; ++j) {
          int gcol = n0 + wn + j * 16 + lrow;
          float v = acc[i][j][r2] + bias[(size_t)e * N + gcol];
          v = v > 0.f ? v : 0.f;
          hout[(size_t)(oe + grow) * H_ + gcol] = f2bf(v);
        }
      }
    }
  }
}

// ---------------- GEMM2: 128^2, SPLITK=2, 32KB LDS, 5 blocks/CU --------------
// (R12/R14-confirmed best G2 config; LDS 5x32=160KB exact, VGPR 60 <= 102)
__global__ __launch_bounds__(256, 5) void ffn_gemm2(
    const unsigned short* __restrict__ hbuf,
    const unsigned short* __restrict__ WT,
    const float* __restrict__ bias,
    const int* __restrict__ cnt, const int* __restrict__ off,
    const int* __restrict__ lists,
    const int* __restrict__ tab, const int* __restrict__ hdr,
    float* __restrict__ out)
{
  constexpr int K = H_;       // 4096
  constexpr int N = D_;       // 1024
  constexpr int KS = K / 2;   // splitk 2
  constexpr int NT = KS / BK; // 32

  __shared__ unsigned short sA[128 * BK];
  __shared__ unsigned short sB[128 * BK];

  const int ntask = hdr[1];
  const int b = blockIdx.x;
  if (b >= ntask) return;
  const int q = ntask >> 3, r = ntask & 7;
  const int x = b & 7, ii = b >> 3;
  const int task = (x < r ? x * (q + 1) : r * (q + 1) + (x - r) * q) + ii;

  const int ent = tab[task];
  const int e  = ent >> 16;
  const int m0 = ((ent >> 8) & 0xff) * 128;
  const int sp = (ent >> 6) & 3;
  const int n0 = (ent & 63) * 128;
  const int k0 = sp * KS;
  const int count = cnt[e];
  const int oe = off[e];
  const int* lst = lists + e * T_;

  const int tid  = threadIdx.x;
  const int lane = tid & 63;
  const int wv   = tid >> 6;
  const int wm   = (wv >> 1) * 64;
  const int wn   = (wv & 1) * 64;

  const int srow   = lane >> 3;
  const int schunk = (lane & 7) * 16;
  const int sgoff  = schunk ^ (srow << 4);

  const char* arow[4];
  const char* brow[4];
#pragma unroll
  for (int i = 0; i < 4; ++i) {
    int rr = i * 32 + wv * 8 + srow;
    int gr = m0 + rr;
    int r2 = (gr < count) ? gr : m0;
    arow[i] = (const char*)(hbuf + (size_t)(oe + r2) * K + k0);
    brow[i] = (const char*)(WT + (size_t)e * N * K + (size_t)(n0 + rr) * K + k0);
  }

  const int lrow = lane & 15;
  const int kg   = lane >> 4;
  const int fswz = (lrow & 7) << 4;

  f32x4 acc[4][4];
#pragma unroll
  for (int i = 0; i < 4; ++i)
#pragma unroll
    for (int j = 0; j < 4; ++j) acc[i][j] = (f32x4){0.f, 0.f, 0.f, 0.f};

#pragma unroll 1
  for (int t = 0; t < NT; ++t) {
    const int kb = t * 128;
#pragma unroll
    for (int i = 0; i < 4; ++i)
      gl16(arow[i] + kb + sgoff, (char*)sA + (i * 32 + wv * 8) * 128);
#pragma unroll
    for (int i = 0; i < 4; ++i)
      gl16(brow[i] + kb + sgoff, (char*)sB + (i * 32 + wv * 8) * 128);
    __syncthreads();
#pragma unroll
    for (int ks = 0; ks < 2; ++ks) {
      bf16x8 af[4], bfm[4];
      const int kbyte = ks * 64 + kg * 16;
#pragma unroll
      for (int i = 0; i < 4; ++i) {
        af[i]  = *(const bf16x8*)((const char*)sA + (wm + i * 16 + lrow) * 128 + (kbyte ^ fswz));
        bfm[i] = *(const bf16x8*)((const char*)sB + (wn + i * 16 + lrow) * 128 + (kbyte ^ fswz));
      }
#pragma unroll
      for (int i = 0; i < 4; ++i)
#pragma unroll
        for (int j = 0; j < 4; ++j)
          acc[i][j] = __builtin_amdgcn_mfma_f32_16x16x32_bf16(af[i], bfm[j], acc[i][j], 0, 0, 0);
    }
    __syncthreads();
  }

  const int rbase = 4 * kg;
#pragma unroll
  for (int i = 0; i < 4; ++i) {
#pragma unroll
    for (int r2 = 0; r2 < 4; ++r2) {
      int row  = wm + i * 16 + rbase + r2;
      int grow = m0 + row;
      if (grow < count) {
        int tok = lst[grow];
#pragma unroll
        for (int j = 0; j < 4; ++j) {
          int gcol = n0 + wn + j * 16 + lrow;
          float bv = (sp == 0) ? bias[(size_t)e * N + gcol] : 0.f;
          atomicAdd(&out[(size_t)tok * D_ + gcol], acc[i][j][r2] + bv);
        }
      }
    }
  }
}

extern "C" void kernel_launch(void* const* d_in, const int* in_sizes, int n_in,
                              void* d_out, int out_size, void* d_ws, size_t ws_size,
                              hipStream_t stream) {
  (void)in_sizes; (void)n_in; (void)out_size;
  const float* x  = (const float*)d_in[0];
  const float* W1 = (const float*)d_in[1];
  const float* b1 = (const float*)d_in[2];
  const float* W2 = (const float*)d_in[3];
  const float* b2 = (const float*)d_in[4];
  const float* Wg = (const float*)d_in[5];
  const float* bg = (const float*)d_in[6];

  float* out    = (float*)d_out;               // [T,D]
  float* scores = out + (size_t)T_ * D_;       // [T,E]

  char* ws = (char*)d_ws;
  int* cnt   = (int*)ws;
  int* off   = (int*)(ws + 32);
  int* hdr   = (int*)(ws + 64);
  int* t1tab = (int*)(ws + 128);
  int* t2tab = (int*)(ws + 128 + 4 * MAXT1);
  int* lists = (int*)(ws + 16384);
  const size_t BASE = 16384 + 131072;
  unsigned short* xb   = (unsigned short*)(ws + BASE);                       // 8 MB
  unsigned short* hbuf = (unsigned short*)(ws + BASE + 8388608);             // 64 MB
  unsigned short* WT1  = (unsigned short*)(ws + BASE + 8388608 + 67108864);  // 64 MB
  const size_t NEED2 = BASE + 8388608 + 67108864ull * 3;                     // ~200.5 MB
  const bool fuse = (ws_size >= NEED2);
  unsigned short* WT2 = fuse ? (WT1 + 67108864 / 2) : WT1;

  hipMemsetAsync(out, 0, (size_t)T_ * D_ * sizeof(float), stream);
  hipMemsetAsync(cnt, 0, 64, stream);

  gate_t1_kernel<<<T_ / 4 + T1BLK, 256, 0, stream>>>(
      x, Wg, bg, scores, xb, cnt, lists, W1, WT1);
  scan_kernel<<<1, 256, 0, stream>>>(cnt, off, hdr, t1tab, t2tab);

  if (fuse) {
    ffn_gemm1<true><<<MAXT1 + T2BLK, 256, 0, stream>>>(
        xb, WT1, b1, cnt, off, lists, t1tab, hdr, hbuf, W2, WT2);
  } else {
    ffn_gemm1<false><<<MAXT1, 256, 0, stream>>>(
        xb, WT1, b1, cnt, off, lists, t1tab, hdr, hbuf, nullptr, nullptr);
    transpose_conv<<<dim3(D_ / 64, H_ / 64, E_), 256, 0, stream>>>(W2, WT2, H_, D_);
  }

  ffn_gemm2<<<MAXT2, 256, 0, stream>>>(
      hbuf, WT2, b2, cnt, off, lists, t2tab, hdr, out);
}

// Round 18
// 410.808 us; speedup vs baseline: 1.3319x; 1.3319x over previous
//
#include <hip/hip_runtime.h>
#include <hip/hip_bf16.h>
#include <stdint.h>

#define B_ 4
#define S_ 1024
#define D_ 1024
#define H_ 4096
#define E_ 8
#define T_ (B_*S_)   // 4096 tokens

#define GBM 128      // GEMM tile
#define BK 64        // 128 bytes bf16 per row per K-tile
#define MAXT1 2432
#define MAXT2 1280
#define T1BLK 8192   // transpose blocks for W1 (64x16x8)
#define T2BLK 8192   // transpose blocks for W2 (16x64x8)

typedef __bf16 bf16x8 __attribute__((ext_vector_type(8)));
typedef float f32x4 __attribute__((ext_vector_type(4)));
typedef unsigned short ushort8 __attribute__((ext_vector_type(8)));
typedef unsigned short ushort4v __attribute__((ext_vector_type(4)));

__device__ __forceinline__ unsigned short f2bf(float f) {
  union { float f; uint32_t u; } v; v.f = f;
  uint32_t u = v.u;
  u += 0x7fff + ((u >> 16) & 1);   // round-to-nearest-even
  return (unsigned short)(u >> 16);
}

// async global->LDS, 16B per lane; LDS dest is WAVE-UNIFORM base, HW scatters lane*16
__device__ __forceinline__ void gl16(const void* g, void* l) {
  __builtin_amdgcn_global_load_lds(
      (const __attribute__((address_space(1))) void*)g,
      (__attribute__((address_space(3))) void*)l,
      16, 0, 0);
}

// ---- shared transpose tile body: fp32 [R][C] slab e -> bf16 [C][R] ----
__device__ __forceinline__ void transpose_tile(
    const float* __restrict__ in, unsigned short* __restrict__ outp,
    int R, int C, int e, int r0, int c0, int t,
    unsigned short (*tile)[66]) {
  const size_t eoff = (size_t)e * R * C;
  {
    const int r = t >> 2, cseg = (t & 3) * 16;
    const float4* s4 = (const float4*)(in + eoff + (size_t)(r0 + r) * C + (c0 + cseg));
    float4 v0 = s4[0], v1 = s4[1], v2 = s4[2], v3 = s4[3];
    ushort8 w0, w1;
    w0[0]=f2bf(v0.x); w0[1]=f2bf(v0.y); w0[2]=f2bf(v0.z); w0[3]=f2bf(v0.w);
    w0[4]=f2bf(v1.x); w0[5]=f2bf(v1.y); w0[6]=f2bf(v1.z); w0[7]=f2bf(v1.w);
    w1[0]=f2bf(v2.x); w1[1]=f2bf(v2.y); w1[2]=f2bf(v2.z); w1[3]=f2bf(v2.w);
    w1[4]=f2bf(v3.x); w1[5]=f2bf(v3.y); w1[6]=f2bf(v3.z); w1[7]=f2bf(v3.w);
    *(ushort8*)&tile[r][cseg]     = w0;
    *(ushort8*)&tile[r][cseg + 8] = w1;
  }
  __syncthreads();
  {
    const int c = t >> 2, rseg = (t & 3) * 16;
    ushort8 w0, w1;
#pragma unroll
    for (int j = 0; j < 8; ++j) {
      w0[j] = tile[rseg + j][c];
      w1[j] = tile[rseg + 8 + j][c];
    }
    unsigned short* dst = outp + eoff + (size_t)(c0 + c) * R + (r0 + rseg);
    *(ushort8*)dst       = w0;
    *(ushort8*)(dst + 8) = w1;
  }
}

// standalone transpose (fallback path when ws too small to fuse)
__global__ __launch_bounds__(256) void transpose_conv(
    const float* __restrict__ in, unsigned short* __restrict__ outp,
    int R, int C) {
  __shared__ unsigned short tile[64][66];
  transpose_tile(in, outp, R, C, blockIdx.z, blockIdx.y * 64, blockIdx.x * 64,
                 threadIdx.x, tile);
}

// ---------------- gating + x->bf16 fused, with W1-transpose blocks appended --
__global__ __launch_bounds__(256) void gate_t1_kernel(
    const float* __restrict__ x, const float* __restrict__ Wg,
    const float* __restrict__ bg, float* __restrict__ scores,
    unsigned short* __restrict__ xb,
    int* __restrict__ cnt, int* __restrict__ lists,
    const float* __restrict__ W1, unsigned short* __restrict__ WT1) {
  __shared__ unsigned short tile[64][66];
  if (blockIdx.x >= T_ / 4) {
    // W1 [E][D][H] -> W1T [E][H][D]: R=D(16 r-tiles), C=H(64 c-tiles)
    int bid = blockIdx.x - T_ / 4;
    int e = bid >> 10, rem = bid & 1023;
    int cx = rem & 63, ry = rem >> 6;
    transpose_tile(W1, WT1, D_, H_, e, ry * 64, cx * 64, threadIdx.x, tile);
    return;
  }
  int t = blockIdx.x * 4 + (threadIdx.x >> 6);
  int l = threadIdx.x & 63;
  float acc[E_];
#pragma unroll
  for (int e = 0; e < E_; ++e) acc[e] = 0.f;
  const float* xr = x + (size_t)t * D_;
  unsigned short* xbr = xb + (size_t)t * D_;
  for (int k4 = l * 4; k4 < D_; k4 += 256) {
    float4 xv = *(const float4*)(xr + k4);
    ushort4v wq;
    wq[0] = f2bf(xv.x); wq[1] = f2bf(xv.y); wq[2] = f2bf(xv.z); wq[3] = f2bf(xv.w);
    *(ushort4v*)(xbr + k4) = wq;
#pragma unroll
    for (int q = 0; q < 4; ++q) {
      float xs = (q == 0) ? xv.x : (q == 1) ? xv.y : (q == 2) ? xv.z : xv.w;
      const float4* w = (const float4*)(Wg + (size_t)(k4 + q) * E_);
      float4 w0 = w[0], w1 = w[1];
      acc[0] += xs * w0.x; acc[1] += xs * w0.y; acc[2] += xs * w0.z; acc[3] += xs * w0.w;
      acc[4] += xs * w1.x; acc[5] += xs * w1.y; acc[6] += xs * w1.z; acc[7] += xs * w1.w;
    }
  }
#pragma unroll
  for (int off = 32; off > 0; off >>= 1)
#pragma unroll
    for (int e = 0; e < E_; ++e) acc[e] += __shfl_xor(acc[e], off, 64);
  if (l == 0) {
    float s[E_];
#pragma unroll
    for (int e = 0; e < E_; ++e) {
      s[e] = acc[e] + bg[e];
      scores[(size_t)t * E_ + e] = s[e];
    }
    int i1 = 0; float m1 = -1e30f;
#pragma unroll
    for (int e = 0; e < E_; ++e) if (s[e] > m1) { m1 = s[e]; i1 = e; }
    int i2 = -1; float m2 = -1e30f;
#pragma unroll
    for (int e = 0; e < E_; ++e) if (e != i1 && s[e] > m2) { m2 = s[e]; i2 = e; }
    int p1 = atomicAdd(&cnt[i1], 1); lists[i1 * T_ + p1] = t;
    int p2 = atomicAdd(&cnt[i2], 1); lists[i2 * T_ + p2] = t;
  }
}

// scan, parallel: G1 thread (e*32+nt) writes its mt run; G2 thread e*16+(sp*8+nt).
// word: e<<16 | mt<<8 | sp<<6 | nt.  G1 order (e,nt,mt); G2 order (e,sp,nt,mt).
__global__ void scan_kernel(const int* __restrict__ cnt, int* __restrict__ off,
                            int* __restrict__ hdr, int* __restrict__ t1tab,
                            int* __restrict__ t2tab) {
  int mt[E_], offl[E_];
  int o = 0;
  for (int e = 0; e < E_; ++e) {
    offl[e] = o; o += cnt[e];
    mt[e] = (cnt[e] + GBM - 1) / GBM;
  }
  const int t = threadIdx.x;
  {
    int e = t >> 5, nt = t & 31;
    int s1 = 0;
    for (int q = 0; q < e; ++q) s1 += mt[q] * (H_ / GBM);
    int base = s1 + nt * mt[e];
    for (int m = 0; m < mt[e]; ++m) t1tab[base + m] = (e << 16) | (m << 8) | nt;
  }
  if (t < 128) {
    int e = t >> 4, idx = t & 15, sp = idx >> 3, nt = idx & 7;
    int s2 = 0;
    for (int q = 0; q < e; ++q) s2 += mt[q] * 2 * (D_ / GBM);
    int base = s2 + (sp * (D_ / GBM) + nt) * mt[e];
    for (int m = 0; m < mt[e]; ++m)
      t2tab[base + m] = (e << 16) | (m << 8) | (sp << 6) | nt;
  }
  if (t == 0) {
    int s1 = 0, s2 = 0;
    for (int e = 0; e < E_; ++e) {
      s1 += mt[e] * (H_ / GBM); s2 += mt[e] * 2 * (D_ / GBM);
      off[e] = offl[e];
    }
    hdr[0] = s1; hdr[1] = s2;
  }
}

// ---------------- grouped per-expert GEMM: 128^2 m97-structure ---------------
// Best measured config (R12, 412us total): (256,4), 32KB LDS, ~4 blocks/CU.
// FUSET2: blocks beyond MAXT1 run W2-transpose tiles, backfilling the
// latency-stalled CUs during GEMM1.
template <int LAYER, int SPLITK, bool FUSET2>
__global__ __launch_bounds__(256, 4) void ffn_gemm(
    const unsigned short* __restrict__ xb,
    const unsigned short* __restrict__ hbuf,
    const unsigned short* __restrict__ WT,
    const float* __restrict__ bias,
    const int* __restrict__ cnt, const int* __restrict__ off,
    const int* __restrict__ lists,
    const int* __restrict__ tab, const int* __restrict__ hdr,
    unsigned short* __restrict__ hout,
    float* __restrict__ out,
    const float* __restrict__ Wsrc, unsigned short* __restrict__ WTdst)
{
  constexpr int K = (LAYER == 1) ? D_ : H_;
  constexpr int N = (LAYER == 1) ? H_ : D_;
  constexpr int KS = K / SPLITK;
  constexpr int NT = KS / BK;

  __shared__ unsigned short sA[GBM * BK];   // 16 KB
  __shared__ unsigned short sB[GBM * BK];   // 16 KB

  if (FUSET2 && blockIdx.x >= MAXT1) {
    // W2 [E][H][D] -> W2T [E][D][H]: R=H(64 r-tiles), C=D(16 c-tiles)
    int bid = blockIdx.x - MAXT1;
    int e = bid >> 10, rem = bid & 1023;
    int cx = rem & 15, ry = rem >> 4;
    transpose_tile(Wsrc, WTdst, H_, D_, e, ry * 64, cx * 64, threadIdx.x,
                   (unsigned short (*)[66])sA);
    return;
  }

  const int ntask = hdr[LAYER - 1];
  const int b = blockIdx.x;
  if (b >= ntask) return;
  // bijective XCD-chunk swizzle (m204): XCD x owns a contiguous task range.
  const int q = ntask >> 3, r = ntask & 7;
  const int x = b & 7, ii = b >> 3;
  const int task = (x < r ? x * (q + 1) : r * (q + 1) + (x - r) * q) + ii;

  const int ent = tab[task];
  const int e  = ent >> 16;
  const int m0 = ((ent >> 8) & 0xff) * GBM;
  const int sp = (ent >> 6) & 3;
  const int n0 = (ent & 63) * GBM;
  const int k0 = sp * KS;
  const int count = cnt[e];
  const int oe = off[e];
  const int* lst = lists + e * T_;

  const int tid  = threadIdx.x;
  const int lane = tid & 63;
  const int wv   = tid >> 6;
  const int wm   = (wv >> 1) * 64;
  const int wn   = (wv & 1) * 64;

  const int srow   = lane >> 3;
  const int schunk = (lane & 7) * 16;
  const int sgoff  = schunk ^ (srow << 4);

  const char* arow[4];
  const char* brow[4];
#pragma unroll
  for (int i = 0; i < 4; ++i) {
    int rr = i * 32 + wv * 8 + srow;
    int gr = m0 + rr;
    if (LAYER == 1) {
      int tok = (gr < count) ? lst[gr] : lst[m0];
      arow[i] = (const char*)(xb + (size_t)tok * K + k0);
    } else {
      int r2 = (gr < count) ? gr : m0;
      arow[i] = (const char*)(hbuf + (size_t)(oe + r2) * K + k0);
    }
    brow[i] = (const char*)(WT + (size_t)e * N * K + (size_t)(n0 + rr) * K + k0);
  }

  const int lrow = lane & 15;
  const int kg   = lane >> 4;
  const int fswz = (lrow & 7) << 4;

  f32x4 acc[4][4];
#pragma unroll
  for (int i = 0; i < 4; ++i)
#pragma unroll
    for (int j = 0; j < 4; ++j) acc[i][j] = (f32x4){0.f, 0.f, 0.f, 0.f};

#pragma unroll 1
  for (int t = 0; t < NT; ++t) {
    const int kb = t * 128;   // bytes along K
#pragma unroll
    for (int i = 0; i < 4; ++i)
      gl16(arow[i] + kb + sgoff, (char*)sA + (i * 32 + wv * 8) * 128);
#pragma unroll
    for (int i = 0; i < 4; ++i)
      gl16(brow[i] + kb + sgoff, (char*)sB + (i * 32 + wv * 8) * 128);
    __syncthreads();   // drains vmcnt -> tile ready; cross-block TLP hides it
#pragma unroll
    for (int ks = 0; ks < 2; ++ks) {
      bf16x8 af[4], bfm[4];
      const int kbyte = ks * 64 + kg * 16;
#pragma unroll
      for (int i = 0; i < 4; ++i) {
        af[i]  = *(const bf16x8*)((const char*)sA + (wm + i * 16 + lrow) * 128 + (kbyte ^ fswz));
        bfm[i] = *(const bf16x8*)((const char*)sB + (wn + i * 16 + lrow) * 128 + (kbyte ^ fswz));
      }
#pragma unroll
      for (int i = 0; i < 4; ++i)
#pragma unroll
        for (int j = 0; j < 4; ++j)
          acc[i][j] = __builtin_amdgcn_mfma_f32_16x16x32_bf16(af[i], bfm[j], acc[i][j], 0, 0, 0);
    }
    __syncthreads();   // all reads done before next stage overwrites
  }

  // ---- epilogue ----
  const int rbase = 4 * kg;
#pragma unroll
  for (int i = 0; i < 4; ++i) {
#pragma unroll
    for (int r2 = 0; r2 < 4; ++r2) {
      int row  = wm + i * 16 + rbase + r2;
      int grow = m0 + row;
      if (grow < count) {
#pragma unroll
        for (int j = 0; j < 4; ++j) {
          int col  = wn + j * 16 + lrow;
          int gcol = n0 + col;
          float bv = (SPLITK == 1 || sp == 0) ? bias[(size_t)e * N + gcol] : 0.f;
          float v = acc[i][j][r2] + bv;
          if (LAYER == 1) {
            v = v > 0.f ? v : 0.f;
            hout[(size_t)(oe + grow) * H_ + gcol] = f2bf(v);
          } else {
            int tok = lst[grow];
            atomicAdd(&out[(size_t)tok * D_ + gcol], v);
          }
        }
      }
    }
  }
}

extern "C" void kernel_launch(void* const* d_in, const int* in_sizes, int n_in,
                              void* d_out, int out_size, void* d_ws, size_t ws_size,
                              hipStream_t stream) {
  (void)in_sizes; (void)n_in; (void)out_size;
  const float* x  = (const float*)d_in[0];
  const float* W1 = (const float*)d_in[1];
  const float* b1 = (const float*)d_in[2];
  const float* W2 = (const float*)d_in[3];
  const float* b2 = (const float*)d_in[4];
  const float* Wg = (const float*)d_in[5];
  const float* bg = (const float*)d_in[6];

  float* out    = (float*)d_out;               // [T,D]
  float* scores = out + (size_t)T_ * D_;       // [T,E]

  char* ws = (char*)d_ws;
  int* cnt   = (int*)ws;                                   // 32 B
  int* off   = (int*)(ws + 32);                            // 32 B
  int* hdr   = (int*)(ws + 64);                            // 8 B
  int* t1tab = (int*)(ws + 128);                           // 9728 B
  int* t2tab = (int*)(ws + 10240);                         // 5120 B
  int* lists = (int*)(ws + 16384);                         // 128 KB
  const size_t BASE = 16384 + 131072;
  unsigned short* xb   = (unsigned short*)(ws + BASE);                       // 8 MB
  unsigned short* hbuf = (unsigned short*)(ws + BASE + 8388608);             // 64 MB
  unsigned short* WT1  = (unsigned short*)(ws + BASE + 8388608 + 67108864);  // 64 MB
  const size_t NEED2 = BASE + 8388608 + 67108864ull * 3;                     // ~200.5 MB
  const bool fuse = (ws_size >= NEED2);
  unsigned short* WT2 = fuse ? (WT1 + 67108864 / 2) : WT1;   // second 64MB slab

  hipMemsetAsync(out, 0, (size_t)T_ * D_ * sizeof(float), stream);
  hipMemsetAsync(cnt, 0, 64, stream);

  // gating + x->bf16 + W1 transpose, one launch
  gate_t1_kernel<<<T_ / 4 + T1BLK, 256, 0, stream>>>(
      x, Wg, bg, scores, xb, cnt, lists, W1, WT1);
  scan_kernel<<<1, 256, 0, stream>>>(cnt, off, hdr, t1tab, t2tab);

  if (fuse) {
    // GEMM1 with W2-transpose blocks appended (backfill stalled CUs)
    ffn_gemm<1, 1, true><<<MAXT1 + T2BLK, 256, 0, stream>>>(
        xb, hbuf, WT1, b1, cnt, off, lists, t1tab, hdr, hbuf, nullptr, W2, WT2);
  } else {
    ffn_gemm<1, 1, false><<<MAXT1, 256, 0, stream>>>(
        xb, hbuf, WT1, b1, cnt, off, lists, t1tab, hdr, hbuf, nullptr, nullptr, nullptr);
    transpose_conv<<<dim3(D_ / 64, H_ / 64, E_), 256, 0, stream>>>(W2, WT2, H_, D_);
  }

  ffn_gemm<2, 2, false><<<MAXT2, 256, 0, stream>>>(
      xb, hbuf, WT2, b2, cnt, off, lists, t2tab, hdr, nullptr, out, nullptr, nullptr);
}